// Round 18
// baseline (44.594 us; speedup 1.0000x reference)
//
#include <hip/hip_runtime.h>
#include <hip/hip_bf16.h>
#include <math.h>

#define NEG_SLOPE 0.2f
#define LN_EPS 1e-5f

constexpr int B = 64, A = 256, L = 1024, D = 128;

typedef float f32x4 __attribute__((ext_vector_type(4)));
typedef float f32x16 __attribute__((ext_vector_type(16)));
typedef short bf16x8 __attribute__((ext_vector_type(8)));

__device__ __forceinline__ ushort f2bf(float x) {
    __hip_bfloat16 h = __float2bfloat16(x);
    return *reinterpret_cast<ushort*>(&h);
}
__device__ __forceinline__ float bf2f(ushort x) {
    unsigned u = ((unsigned)x) << 16;
    return __uint_as_float(u);
}
__device__ __forceinline__ void gl_lds16(const void* g, void* l) {
    __builtin_amdgcn_global_load_lds(
        (const __attribute__((address_space(1))) unsigned int*)g,
        (__attribute__((address_space(3))) unsigned int*)l, 16, 0, 0);
}

// ---------------------------------------------------------------------------
// K1 "prep" (R11-verified): u = W_mol@w_am, v = W_nb@w_aa,
// c0 = b_mol.w_am + b_al, c1 = b_nb.w_aa, WB[e][d] = bf16(W_nb[d][e]).
// ---------------------------------------------------------------------------
__global__ void prep_kernel(const float* __restrict__ Wmol, const float* __restrict__ bmol,
                            const float* __restrict__ wam, const float* __restrict__ bal,
                            const float* __restrict__ Wnb, const float* __restrict__ bnb,
                            const float* __restrict__ waa,
                            float* __restrict__ u, float* __restrict__ v,
                            float* __restrict__ c0, float* __restrict__ c1,
                            ushort* __restrict__ WB) {
    __shared__ float redU[2], redV[2], redC0[2], redC1[2];
    const int i = blockIdx.x, e = threadIdx.x;
    const int lane = e & 63, wv = e >> 6;
    float wnb_ie = Wnb[i * D + e];
    WB[e * D + i] = f2bf(wnb_ie);
    float pu = Wmol[i * D + e] * wam[e];
    float pv = wnb_ie * waa[e];
    float q0 = (i == 0) ? bmol[e] * wam[e] : 0.f;
    float q1 = (i == 0) ? bnb[e] * waa[e] : 0.f;
    #pragma unroll
    for (int o = 1; o < 64; o <<= 1) {
        pu += __shfl_xor(pu, o); pv += __shfl_xor(pv, o);
        q0 += __shfl_xor(q0, o); q1 += __shfl_xor(q1, o);
    }
    if (lane == 0) { redU[wv] = pu; redV[wv] = pv; redC0[wv] = q0; redC1[wv] = q1; }
    __syncthreads();
    if (e == 0) {
        u[i] = redU[0] + redU[1];
        v[i] = redV[0] + redV[1];
        if (i == 0) { c0[0] = redC0[0] + redC0[1] + bal[0];
                      c1[0] = redC1[0] + redC1[1]; }
    }
}

// ---------------------------------------------------------------------------
// K2 "pre2" (R15-verified): 512 smol blocks + 1024 trans blocks.
// ---------------------------------------------------------------------------
__global__ __launch_bounds__(256) void pre2_kernel(
    const float* __restrict__ molf, const float* __restrict__ atom,
    const float* __restrict__ smask,
    const float* __restrict__ u, const float* __restrict__ v,
    const float* __restrict__ c0p, const float* __restrict__ c1p,
    float* __restrict__ smolG, ushort* __restrict__ atomT,
    float* __restrict__ sM) {
    const int bid = blockIdx.x;
    const int tid = threadIdx.x;
    __shared__ __align__(16) ushort Ls[64][132];

    if (bid < 512) {
        const int r = tid >> 3, q = tid & 7;
        const int row = bid * 32 + r;
        const float* xp = molf + (size_t)row * D + q * 16;
        float p = 0.f;
        #pragma unroll
        for (int k = 0; k < 4; ++k) {
            float4 xv = *(const float4*)&xp[k * 4];
            float4 uv = *(const float4*)&u[q * 16 + k * 4];
            p += xv.x * uv.x + xv.y * uv.y + xv.z * uv.z + xv.w * uv.w;
        }
        p += __shfl_xor(p, 1); p += __shfl_xor(p, 2); p += __shfl_xor(p, 4);
        if (q == 0) smolG[row] = p + c0p[0];
        return;
    }

    const int cc = bid - 512;
    const int x = cc & 7, j = cc >> 3;
    const int b = x + 8 * (j & 7);
    const int l0 = (j >> 3) * 64;
    const int q = tid & 31, rg = tid >> 5;
    const float4 vq = *(const float4*)&v[q * 4];
    const float c1 = c1p[0];

    #pragma unroll
    for (int k = 0; k < 8; ++k) {
        const int l = rg * 8 + k;
        float4 xv = *(const float4*)&atom[((size_t)b * L + l0 + l) * D + q * 4];
        float dot = xv.x * vq.x + xv.y * vq.y + xv.z * vq.z + xv.w * vq.w;
        dot += __shfl_xor(dot, 1);  dot += __shfl_xor(dot, 2);
        dot += __shfl_xor(dot, 4);  dot += __shfl_xor(dot, 8);
        dot += __shfl_xor(dot, 16);
        union { ushort us[4]; uint2 u2; } pk;
        pk.us[0] = f2bf(xv.x); pk.us[1] = f2bf(xv.y);
        pk.us[2] = f2bf(xv.z); pk.us[3] = f2bf(xv.w);
        *(uint2*)&Ls[l][q * 4] = pk.u2;
        if (q == 0) {
            float msk = smask[(size_t)b * L + l0 + l];
            sM[(size_t)b * L + l0 + l] = (msk > -0.5f) ? (dot + c1) : -1e30f;
        }
    }
    __syncthreads();
    {
        const int d = tid >> 1, h = tid & 1;
        #pragma unroll
        for (int jj = 0; jj < 4; ++jj) {
            alignas(16) ushort tmp[8];
            #pragma unroll
            for (int m = 0; m < 8; ++m) tmp[m] = Ls[h * 32 + jj * 8 + m][d];
            *(int4*)&atomT[((size_t)(b * 128 + d) << 10) + l0 + h * 32 + jj * 8] =
                *(int4*)tmp;
        }
    }
}

// ---------------------------------------------------------------------------
// K3 "pv" (R11/R14-verified): 512 blocks (b, lq, ah), 2 blocks/CU. Stage one
// 64 KB atomT tile via gl_lds (pre-swizzled source), ONE barrier, pure MFMA.
// psum + bf16 partials (MFMA-native layout) to workspace.
// ---------------------------------------------------------------------------
__global__ __launch_bounds__(256, 2) void pv_kernel(
    const ushort* __restrict__ atomT, const float* __restrict__ sM_g,
    const float* __restrict__ smolG,
    uint2* __restrict__ PP, float* __restrict__ psumP) {
    __shared__ __align__(16) ushort Ta[128][256];
    __shared__ ushort eT[256], fT[256];

    const int bid = blockIdx.x;
    const int x = bid & 7, j = bid >> 3;
    const int b = x + 8 * (j & 7);
    const int rest = j >> 3;
    const int lq = rest >> 1, ah = rest & 1;
    const int tid = threadIdx.x;
    const int w = tid >> 6, lane = tid & 63;
    const int al = lane & 31, hi = lane >> 5;

    const ushort* atomTb = atomT + (size_t)b * D * L + lq * 256;

    #pragma unroll
    for (int q = 0; q < 16; ++q) {
        const int r0 = w * 32 + q * 2;
        const int r = r0 + hi;
        const ushort* g = atomTb + (size_t)r * L + ((al ^ (r & 15)) << 3);
        gl_lds16(g, (char*)&Ta[r0][0]);
    }
    {
        float s = sM_g[(size_t)b * L + lq * 256 + tid];
        eT[tid] = f2bf(__expf(s));
        fT[tid] = f2bf(__expf(NEG_SLOPE * s));
    }
    const int aG = ah * 128 + w * 32 + al;
    const float smv = smolG[(size_t)b * A + aG];
    const float ea = __expf(smv), fa = __expf(NEG_SLOPE * smv);
    __syncthreads();

    f32x16 acc[4] = {};
    float psum = 0.f;
    #pragma unroll 4
    for (int c = 0; c < 16; ++c) {
        const int lb = c * 16 + hi * 8;
        bf16x8 eb = *(const bf16x8*)&eT[lb];
        bf16x8 fb = *(const bf16x8*)&fT[lb];
        bf16x8 pf;
        #pragma unroll
        for (int jj = 0; jj < 8; ++jj) {
            float p_ = fmaxf(ea * bf2f((ushort)eb[jj]), fa * bf2f((ushort)fb[jj]));
            psum += p_;
            pf[jj] = (short)f2bf(p_);
        }
        const int ch = c * 2 + hi;
        #pragma unroll
        for (int dt = 0; dt < 4; ++dt) {
            const int row = dt * 32 + al;
            bf16x8 bf = *(const bf16x8*)((const char*)&Ta[0][0] + row * 512
                                         + ((ch ^ (row & 15)) << 4));
            acc[dt] = __builtin_amdgcn_mfma_f32_32x32x16_bf16(pf, bf, acc[dt], 0, 0, 0);
        }
    }

    psum += __shfl_xor(psum, 32);
    if (hi == 0) psumP[((size_t)b * 4 + lq) * A + aG] = psum;

    const size_t base0 = (((size_t)(b * 4 + lq) * 2 + ah) * 4 + w);
    #pragma unroll
    for (int dt = 0; dt < 4; ++dt) {
        #pragma unroll
        for (int rq = 0; rq < 4; ++rq) {
            union { ushort us[4]; uint2 u2; } pk;
            pk.us[0] = f2bf(acc[dt][rq * 4 + 0]);
            pk.us[1] = f2bf(acc[dt][rq * 4 + 1]);
            pk.us[2] = f2bf(acc[dt][rq * 4 + 2]);
            pk.us[3] = f2bf(acc[dt][rq * 4 + 3]);
            PP[((((base0 * 4 + dt) * 4 + rq) * 2 + hi) * 32) + al] = pk.u2;
        }
    }
}

// ---------------------------------------------------------------------------
// K4 "reduce" (R11/R14-verified): 512 blocks (b, ah, at). Sum 4 lq partials ->
// TT bf16 (chunk-XOR) -> ctx = T.W MFMA + scale + LayerNorm -> out.
// ---------------------------------------------------------------------------
__global__ __launch_bounds__(256) void reduce_kernel(
    const uint2* __restrict__ PP, const float* __restrict__ psumP,
    const float* __restrict__ amask, const ushort* __restrict__ WB,
    const float* __restrict__ bnb,
    const float* __restrict__ gamma, const float* __restrict__ beta,
    float* __restrict__ out) {
    __shared__ __align__(16) ushort TT[32 * 128];
    __shared__ float gbL[256];
    __shared__ float lnP[4][2][16][2];

    const int bid = blockIdx.x;
    const int x = bid & 7, j = bid >> 3;
    const int b = x + 8 * (j & 7);
    const int rest = j >> 3;
    const int ah = rest >> 2, at = rest & 3;
    const int tid = threadIdx.x;
    const int w = tid >> 6, lane = tid & 63;
    const int la = lane & 15, kg = lane >> 4;
    const int xo = la & 7;
    const int aG0 = ah * 128 + at * 32;

    if (tid < 32)      ((float4*)gbL)[tid] = ((const float4*)gamma)[tid];
    else if (tid < 64) ((float4*)gbL)[tid] = ((const float4*)beta)[tid - 32];

    {
        const int rq = tid >> 6, hi2 = (tid >> 5) & 1, al2 = tid & 31;
        float s4[4][4];
        #pragma unroll
        for (int dt = 0; dt < 4; ++dt)
            #pragma unroll
            for (int e = 0; e < 4; ++e) s4[dt][e] = 0.f;
        #pragma unroll
        for (int lq = 0; lq < 4; ++lq) {
            const size_t bb = (((size_t)(b * 4 + lq) * 2 + ah) * 4 + at);
            #pragma unroll
            for (int dt = 0; dt < 4; ++dt) {
                uint2 v = PP[((((bb * 4 + dt) * 4 + rq) * 2 + hi2) * 32) + al2];
                s4[dt][0] += bf2f((ushort)(v.x & 0xffff));
                s4[dt][1] += bf2f((ushort)(v.x >> 16));
                s4[dt][2] += bf2f((ushort)(v.y & 0xffff));
                s4[dt][3] += bf2f((ushort)(v.y >> 16));
            }
        }
        #pragma unroll
        for (int dt = 0; dt < 4; ++dt) {
            const int d = dt * 32 + al2;
            const int cc = d >> 3;
            #pragma unroll
            for (int e = 0; e < 4; ++e) {
                const int arow = e + 8 * rq + 4 * hi2;
                *(ushort*)((char*)TT + arow * 256 + ((cc ^ (arow & 7)) << 4)
                           + (d & 7) * 2) = f2bf(s4[dt][e]);
            }
        }
    }

    bf16x8 wb0[4], wb1[4];
    {
        const ushort* wr0 = WB + (size_t)((2 * w) * 16 + la) * D + kg * 8;
        const ushort* wr1 = WB + (size_t)((2 * w + 1) * 16 + la) * D + kg * 8;
        #pragma unroll
        for (int ks = 0; ks < 4; ++ks) {
            wb0[ks] = *(const bf16x8*)&wr0[ks * 32];
            wb1[ks] = *(const bf16x8*)&wr1[ks * 32];
        }
    }
    float4 bias0 = *(const float4*)&bnb[w * 32 + kg * 4];
    float4 bias1 = *(const float4*)&bnb[w * 32 + 16 + kg * 4];
    const float amA = amask[(size_t)b * A + aG0 + la];
    const float amB = amask[(size_t)b * A + aG0 + 16 + la];
    float psA = 0.f, psB = 0.f;
    #pragma unroll
    for (int lq = 0; lq < 4; ++lq) {
        psA += psumP[((size_t)b * 4 + lq) * A + aG0 + la];
        psB += psumP[((size_t)b * 4 + lq) * A + aG0 + 16 + la];
    }
    __syncthreads();

    const char* TTc = (const char*)TT;
#define LDT(ROW_, KS_) (*(const bf16x8*)(TTc + (ROW_) * 256 + \
                         ((((KS_) * 4 + kg) ^ xo) << 4)))
    f32x4 cA0 = {}, cA1 = {}, cB0 = {}, cB1 = {};
    #pragma unroll
    for (int ks = 0; ks < 4; ++ks) {
        bf16x8 tA = LDT(la, ks);
        bf16x8 tB = LDT(la + 16, ks);
        cA0 = __builtin_amdgcn_mfma_f32_16x16x32_bf16(wb0[ks], tA, cA0, 0, 0, 0);
        cA1 = __builtin_amdgcn_mfma_f32_16x16x32_bf16(wb1[ks], tA, cA1, 0, 0, 0);
        cB0 = __builtin_amdgcn_mfma_f32_16x16x32_bf16(wb0[ks], tB, cB0, 0, 0, 0);
        cB1 = __builtin_amdgcn_mfma_f32_16x16x32_bf16(wb1[ks], tB, cB1, 0, 0, 0);
    }
#undef LDT

    const float scA = amA / psA, scB = amB / psB;
    float xA[8], xB[8];
    float s1A = 0.f, s2A = 0.f, s1B = 0.f, s2B = 0.f;
    const float* bp0 = (const float*)&bias0;
    const float* bp1 = (const float*)&bias1;
    #pragma unroll
    for (int r = 0; r < 4; ++r) {
        xA[r]     = cA0[r] * scA + amA * bp0[r];
        xA[4 + r] = cA1[r] * scA + amA * bp1[r];
        xB[r]     = cB0[r] * scB + amB * bp0[r];
        xB[4 + r] = cB1[r] * scB + amB * bp1[r];
        s1A += xA[r] + xA[4 + r]; s2A += xA[r] * xA[r] + xA[4 + r] * xA[4 + r];
        s1B += xB[r] + xB[4 + r]; s2B += xB[r] * xB[r] + xB[4 + r] * xB[4 + r];
    }
    s1A += __shfl_xor(s1A, 16); s1A += __shfl_xor(s1A, 32);
    s2A += __shfl_xor(s2A, 16); s2A += __shfl_xor(s2A, 32);
    s1B += __shfl_xor(s1B, 16); s1B += __shfl_xor(s1B, 32);
    s2B += __shfl_xor(s2B, 16); s2B += __shfl_xor(s2B, 32);
    if (lane < 16) {
        lnP[w][0][la][0] = s1A; lnP[w][0][la][1] = s2A;
        lnP[w][1][la][0] = s1B; lnP[w][1][la][1] = s2B;
    }
    __syncthreads();
    const float S1A = lnP[0][0][la][0] + lnP[1][0][la][0] + lnP[2][0][la][0] + lnP[3][0][la][0];
    const float S2A = lnP[0][0][la][1] + lnP[1][0][la][1] + lnP[2][0][la][1] + lnP[3][0][la][1];
    const float S1B = lnP[0][1][la][0] + lnP[1][1][la][0] + lnP[2][1][la][0] + lnP[3][1][la][0];
    const float S2B = lnP[0][1][la][1] + lnP[1][1][la][1] + lnP[2][1][la][1] + lnP[3][1][la][1];
    const float muA = S1A * (1.f / 128.f);
    const float rsA = rsqrtf(S2A * (1.f / 128.f) - muA * muA + LN_EPS);
    const float muB = S1B * (1.f / 128.f);
    const float rsB = rsqrtf(S2B * (1.f / 128.f) - muB * muB + LN_EPS);
    const size_t oA = ((size_t)b * A + aG0 + la) * D;
    const size_t oB = ((size_t)b * A + aG0 + 16 + la) * D;
    #pragma unroll
    for (int t = 0; t < 2; ++t) {
        const int e0 = w * 32 + t * 16 + kg * 4;
        float4 g4 = *(float4*)&gbL[e0];
        float4 b4 = *(float4*)&gbL[128 + e0];
        float4 ovA, ovB;
        const float* xpA = &xA[t * 4];
        const float* xpB = &xB[t * 4];
        ((float*)&ovA)[0] = (xpA[0] - muA) * rsA * g4.x + b4.x;
        ((float*)&ovA)[1] = (xpA[1] - muA) * rsA * g4.y + b4.y;
        ((float*)&ovA)[2] = (xpA[2] - muA) * rsA * g4.z + b4.z;
        ((float*)&ovA)[3] = (xpA[3] - muA) * rsA * g4.w + b4.w;
        ((float*)&ovB)[0] = (xpB[0] - muB) * rsB * g4.x + b4.x;
        ((float*)&ovB)[1] = (xpB[1] - muB) * rsB * g4.y + b4.y;
        ((float*)&ovB)[2] = (xpB[2] - muB) * rsB * g4.z + b4.z;
        ((float*)&ovB)[3] = (xpB[3] - muB) * rsB * g4.w + b4.w;
        *(float4*)&out[oA + e0] = ovA;
        *(float4*)&out[oB + e0] = ovB;
    }
}

// ---------------------------------------------------------------------------
extern "C" void kernel_launch(void* const* d_in, const int* in_sizes, int n_in,
                              void* d_out, int out_size, void* d_ws, size_t ws_size,
                              hipStream_t stream) {
    const float* molf  = (const float*)d_in[0];
    const float* atomf = (const float*)d_in[1];
    const float* amask = (const float*)d_in[2];
    const float* smask = (const float*)d_in[3];
    const float* W_mol = (const float*)d_in[4];
    const float* b_mol = (const float*)d_in[5];
    const float* W_nb  = (const float*)d_in[6];
    const float* b_nb  = (const float*)d_in[7];
    const float* w_am  = (const float*)d_in[8];
    const float* w_aa  = (const float*)d_in[9];
    const float* b_al  = (const float*)d_in[10];
    const float* gamma = (const float*)d_in[11];
    const float* beta  = (const float*)d_in[12];
    float* out = (float*)d_out;

    // ws: atomT bf16 [B*D*L] | PP uint2 [B*4*A*D/4] | sM [B*L] | smol [B*A]
    //     | psumP [B*4*A] | u,v [D] | c0,c1 | WB bf16 [D*D]
    ushort* atomT = (ushort*)d_ws;
    uint2* PP     = (uint2*)(atomT + (size_t)B * D * L);
    float* sM     = (float*)(PP + (size_t)B * 4 * A * D / 4);
    float* smolG  = sM + (size_t)B * L;
    float* psumP  = smolG + (size_t)B * A;
    float* u_ws   = psumP + (size_t)B * 4 * A;
    float* v_ws   = u_ws + D;
    float* c0_ws  = v_ws + D;
    float* c1_ws  = c0_ws + 1;
    ushort* WB    = (ushort*)(c1_ws + 1);

    prep_kernel<<<128, 128, 0, stream>>>(W_mol, b_mol, w_am, b_al, W_nb, b_nb,
                                         w_aa, u_ws, v_ws, c0_ws, c1_ws, WB);
    pre2_kernel<<<512 + 1024, 256, 0, stream>>>(molf, atomf, smask, u_ws, v_ws,
                                                c0_ws, c1_ws, smolG, atomT, sM);
    pv_kernel<<<512, 256, 0, stream>>>(atomT, sM, smolG, PP, psumP);
    reduce_kernel<<<512, 256, 0, stream>>>(PP, psumP, amask, WB, b_nb,
                                           gamma, beta, out);
}

// Round 19
// 43.468 us; speedup vs baseline: 1.0259x; 1.0259x over previous
//
#include <hip/hip_runtime.h>
#include <hip/hip_bf16.h>
#include <math.h>

#define NEG_SLOPE 0.2f
#define LN_EPS 1e-5f

constexpr int B = 64, A = 256, L = 1024, D = 128;

typedef float f32x4 __attribute__((ext_vector_type(4)));
typedef float f32x16 __attribute__((ext_vector_type(16)));
typedef short bf16x8 __attribute__((ext_vector_type(8)));

__device__ __forceinline__ ushort f2bf(float x) {
    __hip_bfloat16 h = __float2bfloat16(x);
    return *reinterpret_cast<ushort*>(&h);
}
__device__ __forceinline__ float bf2f(ushort x) {
    unsigned u = ((unsigned)x) << 16;
    return __uint_as_float(u);
}
__device__ __forceinline__ void gl_lds16(const void* g, void* l) {
    __builtin_amdgcn_global_load_lds(
        (const __attribute__((address_space(1))) unsigned int*)g,
        (__attribute__((address_space(3))) unsigned int*)l, 16, 0, 0);
}

// ---------------------------------------------------------------------------
// K1 "prep" (R11-verified): u = W_mol@w_am, v = W_nb@w_aa,
// c0 = b_mol.w_am + b_al, c1 = b_nb.w_aa, WB[e][d] = bf16(W_nb[d][e]).
// ---------------------------------------------------------------------------
__global__ void prep_kernel(const float* __restrict__ Wmol, const float* __restrict__ bmol,
                            const float* __restrict__ wam, const float* __restrict__ bal,
                            const float* __restrict__ Wnb, const float* __restrict__ bnb,
                            const float* __restrict__ waa,
                            float* __restrict__ u, float* __restrict__ v,
                            float* __restrict__ c0, float* __restrict__ c1,
                            ushort* __restrict__ WB) {
    __shared__ float redU[2], redV[2], redC0[2], redC1[2];
    const int i = blockIdx.x, e = threadIdx.x;
    const int lane = e & 63, wv = e >> 6;
    float wnb_ie = Wnb[i * D + e];
    WB[e * D + i] = f2bf(wnb_ie);
    float pu = Wmol[i * D + e] * wam[e];
    float pv = wnb_ie * waa[e];
    float q0 = (i == 0) ? bmol[e] * wam[e] : 0.f;
    float q1 = (i == 0) ? bnb[e] * waa[e] : 0.f;
    #pragma unroll
    for (int o = 1; o < 64; o <<= 1) {
        pu += __shfl_xor(pu, o); pv += __shfl_xor(pv, o);
        q0 += __shfl_xor(q0, o); q1 += __shfl_xor(q1, o);
    }
    if (lane == 0) { redU[wv] = pu; redV[wv] = pv; redC0[wv] = q0; redC1[wv] = q1; }
    __syncthreads();
    if (e == 0) {
        u[i] = redU[0] + redU[1];
        v[i] = redV[0] + redV[1];
        if (i == 0) { c0[0] = redC0[0] + redC0[1] + bal[0];
                      c1[0] = redC1[0] + redC1[1]; }
    }
}

// ---------------------------------------------------------------------------
// K2 "pre2" v3: 512 smol blocks (R15-verified body) + 1024 trans blocks
// rewritten with gl_lds staging: stage 64x128 fp32 atom tile (chunk-XOR
// swizzled via pre-swizzled GLOBAL source), one barrier, then s_atm dot and
// bf16-transpose read LDS only. No dependent global-load chains.
// ---------------------------------------------------------------------------
__global__ __launch_bounds__(256) void pre2_kernel(
    const float* __restrict__ molf, const float* __restrict__ atom,
    const float* __restrict__ smask,
    const float* __restrict__ u, const float* __restrict__ v,
    const float* __restrict__ c0p, const float* __restrict__ c1p,
    float* __restrict__ smolG, ushort* __restrict__ atomT,
    float* __restrict__ sM) {
    __shared__ __align__(16) float Lf[64 * 128];   // 32 KB fp32 tile (swizzled)
    const int bid = blockIdx.x;
    const int tid = threadIdx.x;

    if (bid < 512) {
        // ---- smol: rows [bid*32, bid*32+32)  (R15-verified)
        const int r = tid >> 3, q = tid & 7;
        const int row = bid * 32 + r;
        const float* xp = molf + (size_t)row * D + q * 16;
        float p = 0.f;
        #pragma unroll
        for (int k = 0; k < 4; ++k) {
            float4 xv = *(const float4*)&xp[k * 4];
            float4 uv = *(const float4*)&u[q * 16 + k * 4];
            p += xv.x * uv.x + xv.y * uv.y + xv.z * uv.z + xv.w * uv.w;
        }
        p += __shfl_xor(p, 1); p += __shfl_xor(p, 2); p += __shfl_xor(p, 4);
        if (q == 0) smolG[row] = p + c0p[0];
        return;
    }

    // ---- trans chunk (XCD mapping preserved: 512 % 8 == 0)
    const int cc = bid - 512;
    const int x = cc & 7, j = cc >> 3;
    const int b = x + 8 * (j & 7);
    const int l0 = (j >> 3) * 64;
    const int w = tid >> 6, lane = tid & 63;
    const float c1 = c1p[0];

    // stage: 8 gl_lds per wave, each 1 KB = 2 rows. stored[r][pc] =
    // logical[pc ^ (r&31)] (16B chunks) — swizzle applied on global source.
    {
        const float* abase = atom + ((size_t)b * L + l0) * D;
        #pragma unroll
        for (int q = 0; q < 8; ++q) {
            const int r0 = w * 16 + q * 2;
            const int r = r0 + (lane >> 5);
            const float* g = abase + (size_t)r * D + (((lane & 31) ^ (r & 31)) << 2);
            gl_lds16(g, (char*)Lf + r0 * 512);
        }
    }
    __syncthreads();

    // s_atm dot from LDS: thread (l = tid>>2, q = tid&3), 32 d each
    {
        const int l = tid >> 2, q = tid & 3;
        float p = 0.f;
        #pragma unroll
        for (int k = 0; k < 8; ++k) {
            const int pc = (q * 8 + k) ^ (l & 31);
            float4 xv = *(const float4*)((const char*)Lf + l * 512 + pc * 16);
            float4 vv = *(const float4*)&v[q * 32 + k * 4];
            p += xv.x * vv.x + xv.y * vv.y + xv.z * vv.z + xv.w * vv.w;
        }
        p += __shfl_xor(p, 1); p += __shfl_xor(p, 2);
        if (q == 0) {
            float msk = smask[(size_t)b * L + l0 + l];
            sM[(size_t)b * L + l0 + l] = (msk > -0.5f) ? (p + c1) : -1e30f;
        }
    }

    // bf16 transpose from LDS: thread (d = tid>>1, h = tid&1), 32 l each
    {
        const int d = tid >> 1, h = tid & 1;
        const size_t obase = ((size_t)(b * 128 + d) << 10) + l0 + h * 32;
        #pragma unroll
        for (int g4i = 0; g4i < 4; ++g4i) {
            alignas(16) ushort tmp[8];
            #pragma unroll
            for (int m = 0; m < 8; ++m) {
                const int row = h * 32 + g4i * 8 + m;
                const int pc = (d >> 2) ^ (row & 31);
                float val = *(const float*)((const char*)Lf + row * 512
                                            + pc * 16 + (d & 3) * 4);
                tmp[m] = f2bf(val);
            }
            *(int4*)&atomT[obase + g4i * 8] = *(int4*)tmp;
        }
    }
}

// ---------------------------------------------------------------------------
// K3 "pv" (R11/R14/R18-verified): 512 blocks (b, lq, ah), 2 blocks/CU.
// ---------------------------------------------------------------------------
__global__ __launch_bounds__(256, 2) void pv_kernel(
    const ushort* __restrict__ atomT, const float* __restrict__ sM_g,
    const float* __restrict__ smolG,
    uint2* __restrict__ PP, float* __restrict__ psumP) {
    __shared__ __align__(16) ushort Ta[128][256];
    __shared__ ushort eT[256], fT[256];

    const int bid = blockIdx.x;
    const int x = bid & 7, j = bid >> 3;
    const int b = x + 8 * (j & 7);
    const int rest = j >> 3;
    const int lq = rest >> 1, ah = rest & 1;
    const int tid = threadIdx.x;
    const int w = tid >> 6, lane = tid & 63;
    const int al = lane & 31, hi = lane >> 5;

    const ushort* atomTb = atomT + (size_t)b * D * L + lq * 256;

    #pragma unroll
    for (int q = 0; q < 16; ++q) {
        const int r0 = w * 32 + q * 2;
        const int r = r0 + hi;
        const ushort* g = atomTb + (size_t)r * L + ((al ^ (r & 15)) << 3);
        gl_lds16(g, (char*)&Ta[r0][0]);
    }
    {
        float s = sM_g[(size_t)b * L + lq * 256 + tid];
        eT[tid] = f2bf(__expf(s));
        fT[tid] = f2bf(__expf(NEG_SLOPE * s));
    }
    const int aG = ah * 128 + w * 32 + al;
    const float smv = smolG[(size_t)b * A + aG];
    const float ea = __expf(smv), fa = __expf(NEG_SLOPE * smv);
    __syncthreads();

    f32x16 acc[4] = {};
    float psum = 0.f;
    #pragma unroll 4
    for (int c = 0; c < 16; ++c) {
        const int lb = c * 16 + hi * 8;
        bf16x8 eb = *(const bf16x8*)&eT[lb];
        bf16x8 fb = *(const bf16x8*)&fT[lb];
        bf16x8 pf;
        #pragma unroll
        for (int jj = 0; jj < 8; ++jj) {
            float p_ = fmaxf(ea * bf2f((ushort)eb[jj]), fa * bf2f((ushort)fb[jj]));
            psum += p_;
            pf[jj] = (short)f2bf(p_);
        }
        const int ch = c * 2 + hi;
        #pragma unroll
        for (int dt = 0; dt < 4; ++dt) {
            const int row = dt * 32 + al;
            bf16x8 bf = *(const bf16x8*)((const char*)&Ta[0][0] + row * 512
                                         + ((ch ^ (row & 15)) << 4));
            acc[dt] = __builtin_amdgcn_mfma_f32_32x32x16_bf16(pf, bf, acc[dt], 0, 0, 0);
        }
    }

    psum += __shfl_xor(psum, 32);
    if (hi == 0) psumP[((size_t)b * 4 + lq) * A + aG] = psum;

    const size_t base0 = (((size_t)(b * 4 + lq) * 2 + ah) * 4 + w);
    #pragma unroll
    for (int dt = 0; dt < 4; ++dt) {
        #pragma unroll
        for (int rq = 0; rq < 4; ++rq) {
            union { ushort us[4]; uint2 u2; } pk;
            pk.us[0] = f2bf(acc[dt][rq * 4 + 0]);
            pk.us[1] = f2bf(acc[dt][rq * 4 + 1]);
            pk.us[2] = f2bf(acc[dt][rq * 4 + 2]);
            pk.us[3] = f2bf(acc[dt][rq * 4 + 3]);
            PP[((((base0 * 4 + dt) * 4 + rq) * 2 + hi) * 32) + al] = pk.u2;
        }
    }
}

// ---------------------------------------------------------------------------
// K4 "reduce" (R11/R14/R18-verified): 512 blocks (b, ah, at).
// ---------------------------------------------------------------------------
__global__ __launch_bounds__(256) void reduce_kernel(
    const uint2* __restrict__ PP, const float* __restrict__ psumP,
    const float* __restrict__ amask, const ushort* __restrict__ WB,
    const float* __restrict__ bnb,
    const float* __restrict__ gamma, const float* __restrict__ beta,
    float* __restrict__ out) {
    __shared__ __align__(16) ushort TT[32 * 128];
    __shared__ float gbL[256];
    __shared__ float lnP[4][2][16][2];

    const int bid = blockIdx.x;
    const int x = bid & 7, j = bid >> 3;
    const int b = x + 8 * (j & 7);
    const int rest = j >> 3;
    const int ah = rest >> 2, at = rest & 3;
    const int tid = threadIdx.x;
    const int w = tid >> 6, lane = tid & 63;
    const int la = lane & 15, kg = lane >> 4;
    const int xo = la & 7;
    const int aG0 = ah * 128 + at * 32;

    if (tid < 32)      ((float4*)gbL)[tid] = ((const float4*)gamma)[tid];
    else if (tid < 64) ((float4*)gbL)[tid] = ((const float4*)beta)[tid - 32];

    {
        const int rq = tid >> 6, hi2 = (tid >> 5) & 1, al2 = tid & 31;
        float s4[4][4];
        #pragma unroll
        for (int dt = 0; dt < 4; ++dt)
            #pragma unroll
            for (int e = 0; e < 4; ++e) s4[dt][e] = 0.f;
        #pragma unroll
        for (int lq = 0; lq < 4; ++lq) {
            const size_t bb = (((size_t)(b * 4 + lq) * 2 + ah) * 4 + at);
            #pragma unroll
            for (int dt = 0; dt < 4; ++dt) {
                uint2 v = PP[((((bb * 4 + dt) * 4 + rq) * 2 + hi2) * 32) + al2];
                s4[dt][0] += bf2f((ushort)(v.x & 0xffff));
                s4[dt][1] += bf2f((ushort)(v.x >> 16));
                s4[dt][2] += bf2f((ushort)(v.y & 0xffff));
                s4[dt][3] += bf2f((ushort)(v.y >> 16));
            }
        }
        #pragma unroll
        for (int dt = 0; dt < 4; ++dt) {
            const int d = dt * 32 + al2;
            const int cc = d >> 3;
            #pragma unroll
            for (int e = 0; e < 4; ++e) {
                const int arow = e + 8 * rq + 4 * hi2;
                *(ushort*)((char*)TT + arow * 256 + ((cc ^ (arow & 7)) << 4)
                           + (d & 7) * 2) = f2bf(s4[dt][e]);
            }
        }
    }

    bf16x8 wb0[4], wb1[4];
    {
        const ushort* wr0 = WB + (size_t)((2 * w) * 16 + la) * D + kg * 8;
        const ushort* wr1 = WB + (size_t)((2 * w + 1) * 16 + la) * D + kg * 8;
        #pragma unroll
        for (int ks = 0; ks < 4; ++ks) {
            wb0[ks] = *(const bf16x8*)&wr0[ks * 32];
            wb1[ks] = *(const bf16x8*)&wr1[ks * 32];
        }
    }
    float4 bias0 = *(const float4*)&bnb[w * 32 + kg * 4];
    float4 bias1 = *(const float4*)&bnb[w * 32 + 16 + kg * 4];
    const float amA = amask[(size_t)b * A + aG0 + la];
    const float amB = amask[(size_t)b * A + aG0 + 16 + la];
    float psA = 0.f, psB = 0.f;
    #pragma unroll
    for (int lq = 0; lq < 4; ++lq) {
        psA += psumP[((size_t)b * 4 + lq) * A + aG0 + la];
        psB += psumP[((size_t)b * 4 + lq) * A + aG0 + 16 + la];
    }
    __syncthreads();

    const char* TTc = (const char*)TT;
#define LDT(ROW_, KS_) (*(const bf16x8*)(TTc + (ROW_) * 256 + \
                         ((((KS_) * 4 + kg) ^ xo) << 4)))
    f32x4 cA0 = {}, cA1 = {}, cB0 = {}, cB1 = {};
    #pragma unroll
    for (int ks = 0; ks < 4; ++ks) {
        bf16x8 tA = LDT(la, ks);
        bf16x8 tB = LDT(la + 16, ks);
        cA0 = __builtin_amdgcn_mfma_f32_16x16x32_bf16(wb0[ks], tA, cA0, 0, 0, 0);
        cA1 = __builtin_amdgcn_mfma_f32_16x16x32_bf16(wb1[ks], tA, cA1, 0, 0, 0);
        cB0 = __builtin_amdgcn_mfma_f32_16x16x32_bf16(wb0[ks], tB, cB0, 0, 0, 0);
        cB1 = __builtin_amdgcn_mfma_f32_16x16x32_bf16(wb1[ks], tB, cB1, 0, 0, 0);
    }
#undef LDT

    const float scA = amA / psA, scB = amB / psB;
    float xA[8], xB[8];
    float s1A = 0.f, s2A = 0.f, s1B = 0.f, s2B = 0.f;
    const float* bp0 = (const float*)&bias0;
    const float* bp1 = (const float*)&bias1;
    #pragma unroll
    for (int r = 0; r < 4; ++r) {
        xA[r]     = cA0[r] * scA + amA * bp0[r];
        xA[4 + r] = cA1[r] * scA + amA * bp1[r];
        xB[r]     = cB0[r] * scB + amB * bp0[r];
        xB[4 + r] = cB1[r] * scB + amB * bp1[r];
        s1A += xA[r] + xA[4 + r]; s2A += xA[r] * xA[r] + xA[4 + r] * xA[4 + r];
        s1B += xB[r] + xB[4 + r]; s2B += xB[r] * xB[r] + xB[4 + r] * xB[4 + r];
    }
    s1A += __shfl_xor(s1A, 16); s1A += __shfl_xor(s1A, 32);
    s2A += __shfl_xor(s2A, 16); s2A += __shfl_xor(s2A, 32);
    s1B += __shfl_xor(s1B, 16); s1B += __shfl_xor(s1B, 32);
    s2B += __shfl_xor(s2B, 16); s2B += __shfl_xor(s2B, 32);
    if (lane < 16) {
        lnP[w][0][la][0] = s1A; lnP[w][0][la][1] = s2A;
        lnP[w][1][la][0] = s1B; lnP[w][1][la][1] = s2B;
    }
    __syncthreads();
    const float S1A = lnP[0][0][la][0] + lnP[1][0][la][0] + lnP[2][0][la][0] + lnP[3][0][la][0];
    const float S2A = lnP[0][0][la][1] + lnP[1][0][la][1] + lnP[2][0][la][1] + lnP[3][0][la][1];
    const float S1B = lnP[0][1][la][0] + lnP[1][1][la][0] + lnP[2][1][la][0] + lnP[3][1][la][0];
    const float S2B = lnP[0][1][la][1] + lnP[1][1][la][1] + lnP[2][1][la][1] + lnP[3][1][la][1];
    const float muA = S1A * (1.f / 128.f);
    const float rsA = rsqrtf(S2A * (1.f / 128.f) - muA * muA + LN_EPS);
    const float muB = S1B * (1.f / 128.f);
    const float rsB = rsqrtf(S2B * (1.f / 128.f) - muB * muB + LN_EPS);
    const size_t oA = ((size_t)b * A + aG0 + la) * D;
    const size_t oB = ((size_t)b * A + aG0 + 16 + la) * D;
    #pragma unroll
    for (int t = 0; t < 2; ++t) {
        const int e0 = w * 32 + t * 16 + kg * 4;
        float4 g4 = *(float4*)&gbL[e0];
        float4 b4 = *(float4*)&gbL[128 + e0];
        float4 ovA, ovB;
        const float* xpA = &xA[t * 4];
        const float* xpB = &xB[t * 4];
        ((float*)&ovA)[0] = (xpA[0] - muA) * rsA * g4.x + b4.x;
        ((float*)&ovA)[1] = (xpA[1] - muA) * rsA * g4.y + b4.y;
        ((float*)&ovA)[2] = (xpA[2] - muA) * rsA * g4.z + b4.z;
        ((float*)&ovA)[3] = (xpA[3] - muA) * rsA * g4.w + b4.w;
        ((float*)&ovB)[0] = (xpB[0] - muB) * rsB * g4.x + b4.x;
        ((float*)&ovB)[1] = (xpB[1] - muB) * rsB * g4.y + b4.y;
        ((float*)&ovB)[2] = (xpB[2] - muB) * rsB * g4.z + b4.z;
        ((float*)&ovB)[3] = (xpB[3] - muB) * rsB * g4.w + b4.w;
        *(float4*)&out[oA + e0] = ovA;
        *(float4*)&out[oB + e0] = ovB;
    }
}

// ---------------------------------------------------------------------------
extern "C" void kernel_launch(void* const* d_in, const int* in_sizes, int n_in,
                              void* d_out, int out_size, void* d_ws, size_t ws_size,
                              hipStream_t stream) {
    const float* molf  = (const float*)d_in[0];
    const float* atomf = (const float*)d_in[1];
    const float* amask = (const float*)d_in[2];
    const float* smask = (const float*)d_in[3];
    const float* W_mol = (const float*)d_in[4];
    const float* b_mol = (const float*)d_in[5];
    const float* W_nb  = (const float*)d_in[6];
    const float* b_nb  = (const float*)d_in[7];
    const float* w_am  = (const float*)d_in[8];
    const float* w_aa  = (const float*)d_in[9];
    const float* b_al  = (const float*)d_in[10];
    const float* gamma = (const float*)d_in[11];
    const float* beta  = (const float*)d_in[12];
    float* out = (float*)d_out;

    // ws: atomT bf16 [B*D*L] | PP uint2 [B*4*A*D/4] | sM [B*L] | smol [B*A]
    //     | psumP [B*4*A] | u,v [D] | c0,c1 | WB bf16 [D*D]
    ushort* atomT = (ushort*)d_ws;
    uint2* PP     = (uint2*)(atomT + (size_t)B * D * L);
    float* sM     = (float*)(PP + (size_t)B * 4 * A * D / 4);
    float* smolG  = sM + (size_t)B * L;
    float* psumP  = smolG + (size_t)B * A;
    float* u_ws   = psumP + (size_t)B * 4 * A;
    float* v_ws   = u_ws + D;
    float* c0_ws  = v_ws + D;
    float* c1_ws  = c0_ws + 1;
    ushort* WB    = (ushort*)(c1_ws + 1);

    prep_kernel<<<128, 128, 0, stream>>>(W_mol, b_mol, w_am, b_al, W_nb, b_nb,
                                         w_aa, u_ws, v_ws, c0_ws, c1_ws, WB);
    pre2_kernel<<<512 + 1024, 256, 0, stream>>>(molf, atomf, smask, u_ws, v_ws,
                                                c0_ws, c1_ws, smolG, atomT, sM);
    pv_kernel<<<512, 256, 0, stream>>>(atomT, sM, smolG, PP, psumP);
    reduce_kernel<<<512, 256, 0, stream>>>(PP, psumP, amask, WB, b_nb,
                                           gamma, beta, out);
}